// Round 16
// baseline (487.868 us; speedup 1.0000x reference)
//
#include <hip/hip_runtime.h>
#include <hip/hip_bf16.h>

// AttentionLayer: out = softmax(32 * (xWq^T)(yWk^T)^T + causal) @ (zWv^T)
// N=8, S=T=2048, D=1024. All f32 in/out.
//
// R16: R14 base (best, 480us; R15 fusion was neutral -> dropped) with qk_bt
// switched to v_mfma_f32_32x32x16_bf16: 24 vs 48 MFMA/K-step (half issue
// pressure, 17% less matrix-pipe time, 15% higher ceiling 2382 vs 2075).
// A/B frag: row=lane&31, k=(lane>>5)*8+e (mirror of verified 16x16 map);
// C/D: col=lane&31, row=(reg&3)+8*(reg>>2)+4*(lane>>5) (m74/m101).
// Everything else R14 verbatim.

typedef __attribute__((ext_vector_type(4))) float f32x4;
typedef __attribute__((ext_vector_type(16))) float f32x16;
typedef __attribute__((ext_vector_type(8))) short bf16x8;
typedef __attribute__((ext_vector_type(4))) short s16x4;

#define DEVI __device__ __forceinline__

DEVI unsigned short f2bf(float x) {
  union { float f; unsigned u; } v; v.f = x;
  unsigned r = v.u + 0x7FFFu + ((v.u >> 16) & 1u);
  return (unsigned short)(r >> 16);
}
DEVI float bf2f(unsigned short b) {
  union { float f; unsigned u; } v; v.u = ((unsigned)b) << 16;
  return v.f;
}

DEVI void gload16(const void* g, void* l) {
#if __has_builtin(__builtin_amdgcn_global_load_lds)
  typedef __attribute__((address_space(1))) const unsigned int* gas_u32;
  typedef __attribute__((address_space(3))) unsigned int* las_u32;
  __builtin_amdgcn_global_load_lds(
      (gas_u32)(unsigned long long)g,
      (las_u32)(unsigned int)(unsigned long long)l, 16, 0, 0);
#else
  *(bf16x8*)l = *(const bf16x8*)g;
#endif
}

DEVI int xcd_swizzle(int bid, int nwg) {
  if (nwg & 7) return bid;
  int cpx = nwg >> 3;
  return (bid & 7) * cpx + (bid >> 3);
}

#define WAITBAR(N) asm volatile("s_waitcnt vmcnt(" #N ")\ns_barrier" ::: "memory")
#define BAR()      asm volatile("s_barrier" ::: "memory")

// Stage one combined plane: 128 rows x 128B, row = [s0 64B | s1 64B],
// XOR-swizzled (chunk ^= row&7), linear LDS dest (256-thread blocks).
DEVI void stage_pair(const unsigned short* __restrict__ s0, long long rs0,
                     const unsigned short* __restrict__ s1, long long rs1,
                     short* lds, int tid) {
#pragma unroll
  for (int it = 0; it < 4; ++it) {
    int ii = it * 256 + tid;
    int r = ii >> 3;
    int c8 = (ii & 7) ^ (r & 7);
    const unsigned short* src = (c8 < 4)
        ? s0 + (long long)r * rs0 + (c8 & 3) * 8
        : s1 + (long long)r * rs1 + (c8 & 3) * 8;
    gload16(src, &lds[ii * 8]);
  }
}

constexpr int NB = 8, SS = 2048, TT = 2048, DD = 1024;
constexpr long long TILE_E = 16384;

// ---------------------------------------------------------------------------
// Elementwise split kernels.
// ---------------------------------------------------------------------------
__global__ __launch_bounds__(256) void split_hl_k(
    const float* __restrict__ in, unsigned short* __restrict__ hi,
    unsigned short* __restrict__ lo, long long n4)
{
  long long i = (long long)blockIdx.x * 256 + threadIdx.x;
  long long stride = (long long)gridDim.x * 256;
  for (; i < n4; i += stride) {
    f32x4 v = ((const f32x4*)in)[i];
    s16x4 h, l;
#pragma unroll
    for (int e = 0; e < 4; ++e) {
      unsigned short hh = f2bf(v[e]);
      h[e] = (short)hh;
      l[e] = (short)f2bf(v[e] - bf2f(hh));
    }
    ((s16x4*)hi)[i] = h;
    ((s16x4*)lo)[i] = l;
  }
}

__global__ __launch_bounds__(256) void split_h_k(
    const float* __restrict__ in, unsigned short* __restrict__ hi, long long n4)
{
  long long i = (long long)blockIdx.x * 256 + threadIdx.x;
  long long stride = (long long)gridDim.x * 256;
  for (; i < n4; i += stride) {
    f32x4 v = ((const f32x4*)in)[i];
    s16x4 h;
#pragma unroll
    for (int e = 0; e < 4; ++e) h[e] = (short)f2bf(v[e]);
    ((s16x4*)hi)[i] = h;
  }
}

// Transpose + split weights (tiny).
__global__ __launch_bounds__(256) void tsplit_k(
    const float* __restrict__ W, unsigned short* __restrict__ Th,
    unsigned short* __restrict__ Tl)
{
  __shared__ float t[64][68];
  int bi = blockIdx.x & 15, bj = blockIdx.x >> 4;
  int tid = threadIdx.x;
  int lr = tid >> 2, lc4 = tid & 3;
#pragma unroll
  for (int q = 0; q < 4; ++q) {
    int col = (lc4 + q * 4) * 4;
    f32x4 v = *(const f32x4*)(W + (long long)(bj * 64 + lr) * DD + bi * 64 + col);
    t[lr][col] = v[0]; t[lr][col + 1] = v[1];
    t[lr][col + 2] = v[2]; t[lr][col + 3] = v[3];
  }
  __syncthreads();
  int orow = tid >> 2, ch = tid & 3;
#pragma unroll
  for (int cc = 0; cc < 2; ++cc) {
    int c0 = (ch + cc * 4) * 8;
    bf16x8 h, l;
#pragma unroll
    for (int e = 0; e < 8; ++e) {
      float v = t[c0 + e][orow];
      unsigned short hh = f2bf(v);
      h[e] = (short)hh;
      l[e] = (short)f2bf(v - bf2f(hh));
    }
    long long o = (long long)(bi * 64 + orow) * DD + bj * 64 + c0;
    *(bf16x8*)(Th + o) = h;
    *(bf16x8*)(Tl + o) = l;
  }
}

// ---------------------------------------------------------------------------
// bt-GEMM (128^2, 2 M-tiles/block, depth-2 counted vmcnt, issue-early).
// ---------------------------------------------------------------------------
template<int NMFMA, bool SPLIT_OUT>
__global__ __launch_bounds__(256, 2) void gemm_bt(
    const unsigned short* __restrict__ Ah_g, const unsigned short* __restrict__ Al_g,
    const unsigned short* __restrict__ Bh_g, const unsigned short* __restrict__ Bl_g,
    unsigned short* __restrict__ Chi, unsigned short* __restrict__ Clo,
    int Nn, int K,
    long long aStride, long long bStride, long long cStride,
    int tilesM, int tilesN)
{
  constexpr int HALF = (NMFMA == 3) ? 16384 : 8192;
  __shared__ short lds[2 * HALF];

  int tid = threadIdx.x;
  int lane = tid & 63, wid = tid >> 6;
  int wr = wid >> 1, wc = wid & 1;
  int l15 = lane & 15, lq = lane >> 4;

  int wg = xcd_swizzle(blockIdx.x, gridDim.x);
  int tilesM2 = tilesM >> 1;
  int tilesPer = tilesM2 * tilesN;
  int b = wg / tilesPer;
  int rem = wg % tilesPer;
  int mt2 = rem / tilesN, nt = rem % tilesN;

  const unsigned short* Bgh = Bh_g + (long long)b * bStride + (long long)nt * 128 * K;
  const unsigned short* Bgl = (NMFMA == 3) ? Bl_g + (long long)b * bStride + (long long)nt * 128 * K : nullptr;

  for (int hm = 0; hm < 2; ++hm) {
    int mt = mt2 + hm * tilesM2;
    const unsigned short* Agh = Ah_g + (long long)b * aStride + (long long)mt * 128 * K;
    const unsigned short* Agl = (NMFMA == 3) ? Al_g + (long long)b * aStride + (long long)mt * 128 * K : nullptr;

    f32x4 acc[4][4];
#pragma unroll
    for (int i = 0; i < 4; ++i)
#pragma unroll
      for (int j = 0; j < 4; ++j) acc[i][j] = (f32x4){0.f, 0.f, 0.f, 0.f};

    auto stage = [&](int t, int h) {
      int k0 = t * 32;
      if constexpr (NMFMA == 3) {
        stage_pair(Agh + k0, K, Agl + k0, K, lds + h * HALF, tid);
        stage_pair(Bgh + k0, K, Bgl + k0, K, lds + h * HALF + 8192, tid);
      } else {
        stage_pair(Agh + k0, K, Bgh + k0, K, lds + h * HALF, tid);
      }
    };

    int NT = K >> 5;
    stage(0, 0);
    stage(1, 1);
    for (int t = 0; t < NT; ++t) {
      int h = t & 1;
      if (t < NT - 1) {
        if constexpr (NMFMA == 3) WAITBAR(8); else WAITBAR(4);
      } else {
        WAITBAR(0);
      }
      if constexpr (NMFMA == 3) {
        const short* U = lds + h * HALF;
        const short* V = U + 8192;
        bf16x8 afh[4], afl[4], bfh[4], bfl[4];
#pragma unroll
        for (int i = 0; i < 4; ++i) {
          int ra = wr * 64 + i * 16 + l15;
          int sa = (ra & 7) << 4;
          afh[i] = *(const bf16x8*)(&U[((ra * 128 + lq * 16) ^ sa) >> 1]);
          afl[i] = *(const bf16x8*)(&U[((ra * 128 + 64 + lq * 16) ^ sa) >> 1]);
          int rb = wc * 64 + i * 16 + l15;
          int sb = (rb & 7) << 4;
          bfh[i] = *(const bf16x8*)(&V[((rb * 128 + lq * 16) ^ sb) >> 1]);
          bfl[i] = *(const bf16x8*)(&V[((rb * 128 + 64 + lq * 16) ^ sb) >> 1]);
        }
        BAR();
        if (t + 2 < NT) stage(t + 2, h);
        __builtin_amdgcn_s_setprio(1);
#pragma unroll
        for (int i = 0; i < 4; ++i)
#pragma unroll
          for (int j = 0; j < 4; ++j) {
            acc[i][j] = __builtin_amdgcn_mfma_f32_16x16x32_bf16(afh[i], bfh[j], acc[i][j], 0, 0, 0);
            acc[i][j] = __builtin_amdgcn_mfma_f32_16x16x32_bf16(afh[i], bfl[j], acc[i][j], 0, 0, 0);
            acc[i][j] = __builtin_amdgcn_mfma_f32_16x16x32_bf16(afl[i], bfh[j], acc[i][j], 0, 0, 0);
          }
        __builtin_amdgcn_s_setprio(0);
      } else {
        const short* W = lds + h * HALF;
        bf16x8 af[4], bfr[4];
#pragma unroll
        for (int i = 0; i < 4; ++i) {
          int ra = wr * 64 + i * 16 + l15;
          af[i] = *(const bf16x8*)(&W[((ra * 128 + lq * 16) ^ ((ra & 7) << 4)) >> 1]);
          int rb = wc * 64 + i * 16 + l15;
          bfr[i] = *(const bf16x8*)(&W[((rb * 128 + 64 + lq * 16) ^ ((rb & 7) << 4)) >> 1]);
        }
        BAR();
        if (t + 2 < NT) stage(t + 2, h);
        __builtin_amdgcn_s_setprio(1);
#pragma unroll
        for (int i = 0; i < 4; ++i)
#pragma unroll
          for (int j = 0; j < 4; ++j)
            acc[i][j] = __builtin_amdgcn_mfma_f32_16x16x32_bf16(af[i], bfr[j], acc[i][j], 0, 0, 0);
        __builtin_amdgcn_s_setprio(0);
      }
    }

    unsigned short* ch = Chi + (long long)b * cStride;
    unsigned short* cl = SPLIT_OUT ? (Clo + (long long)b * cStride) : nullptr;
#pragma unroll
    for (int i = 0; i < 4; ++i)
#pragma unroll
      for (int j = 0; j < 4; ++j)
#pragma unroll
        for (int e = 0; e < 4; ++e) {
          int row = mt * 128 + wr * 64 + i * 16 + lq * 4 + e;
          int col = nt * 128 + wc * 64 + j * 16 + l15;
          float vv = acc[i][j][e];
          unsigned short h = f2bf(vv);
          ch[(long long)row * Nn + col] = h;
          if constexpr (SPLIT_OUT) cl[(long long)row * Nn + col] = f2bf(vv - bf2f(h));
        }
    BAR();
  }
}

// ---------------------------------------------------------------------------
// QK^T: bf16x3, 128x128 lower-triangular tiles, packed output. Issue-early.
// 32x32x16 MFMA: 24 instr/K-step (vs 48). Wave tile 64x64 = 2x2 of 32x32.
// A/B frag: row/col = lane&31, k = (lane>>5)*8 + e. C/D per m74/m101.
// ---------------------------------------------------------------------------
__global__ __launch_bounds__(256, 2) void qk_bt(
    const unsigned short* __restrict__ qh, const unsigned short* __restrict__ ql,
    const unsigned short* __restrict__ kh, const unsigned short* __restrict__ kl,
    float* __restrict__ Sg)
{
  __shared__ short lds[2 * 16384];

  int tid = threadIdx.x;
  int lane = tid & 63, wid = tid >> 6;
  int wr = wid >> 1, wc = wid & 1;
  int l31 = lane & 31, lh = lane >> 5;

  int wg = xcd_swizzle(blockIdx.x, gridDim.x);
  int b = wg / 136;
  int idx = wg % 136;
  int st = (int)((sqrtf(8.f * (float)idx + 1.f) - 1.f) * 0.5f);
  while ((st + 1) * (st + 2) / 2 <= idx) ++st;
  while (st * (st + 1) / 2 > idx) --st;
  int tt = idx - st * (st + 1) / 2;

  const unsigned short* Agh = qh + (long long)b * SS * DD + (long long)st * 128 * DD;
  const unsigned short* Agl = ql + (long long)b * SS * DD + (long long)st * 128 * DD;
  const unsigned short* Bgh = kh + (long long)b * TT * DD + (long long)tt * 128 * DD;
  const unsigned short* Bgl = kl + (long long)b * TT * DD + (long long)tt * 128 * DD;

  f32x16 acc[2][2];
#pragma unroll
  for (int i = 0; i < 2; ++i)
#pragma unroll
    for (int j = 0; j < 2; ++j)
#pragma unroll
      for (int e = 0; e < 16; ++e) acc[i][j][e] = 0.f;

  auto stage = [&](int t, int h) {
    int k0 = t * 32;
    stage_pair(Agh + k0, DD, Agl + k0, DD, lds + h * 16384, tid);
    stage_pair(Bgh + k0, DD, Bgl + k0, DD, lds + h * 16384 + 8192, tid);
  };

  stage(0, 0);
  stage(1, 1);
  for (int t = 0; t < 32; ++t) {
    int h = t & 1;
    if (t < 31) WAITBAR(8); else WAITBAR(0);
    const short* U = lds + h * 16384;
    const short* V = U + 8192;
    // fragments: [tile 0/1][k-half 0/1]; row = wr*64 + ti*32 + l31,
    // k within 32 = kh16*16 + lh*8; hi plane bytes [0,64), lo [64,128).
    bf16x8 ah[2][2], al[2][2], bh[2][2], bl[2][2];
#pragma unroll
    for (int ti = 0; ti < 2; ++ti) {
      int ra = wr * 64 + ti * 32 + l31;
      int sa = (ra & 7) << 4;
      int rb = wc * 64 + ti * 32 + l31;
      int sb = (rb & 7) << 4;
#pragma unroll
      for (int kh16 = 0; kh16 < 2; ++kh16) {
        int ko = (kh16 * 16 + lh * 8) * 2;   // byte offset within 64B half
        ah[ti][kh16] = *(const bf16x8*)(&U[((ra * 128 + ko) ^ sa) >> 1]);
        al[ti][kh16] = *(const bf16x8*)(&U[((ra * 128 + 64 + ko) ^ sa) >> 1]);
        bh[ti][kh16] = *(const bf16x8*)(&V[((rb * 128 + ko) ^ sb) >> 1]);
        bl[ti][kh16] = *(const bf16x8*)(&V[((rb * 128 + 64 + ko) ^ sb) >> 1]);
      }
    }
    BAR();
    if (t + 2 < 32) stage(t + 2, h);
    __builtin_amdgcn_s_setprio(1);
#pragma unroll
    for (int i = 0; i < 2; ++i)
#pragma unroll
      for (int j = 0; j < 2; ++j)
#pragma unroll
        for (int kh16 = 0; kh16 < 2; ++kh16) {
          acc[i][j] = __builtin_amdgcn_mfma_f32_32x32x16_bf16(ah[i][kh16], bh[j][kh16], acc[i][j], 0, 0, 0);
          acc[i][j] = __builtin_amdgcn_mfma_f32_32x32x16_bf16(ah[i][kh16], bl[j][kh16], acc[i][j], 0, 0, 0);
          acc[i][j] = __builtin_amdgcn_mfma_f32_32x32x16_bf16(al[i][kh16], bh[j][kh16], acc[i][j], 0, 0, 0);
        }
    __builtin_amdgcn_s_setprio(0);
  }

  // C/D 32x32 layout: col = lane&31, row = (reg&3) + 8*(reg>>2) + 4*(lane>>5)
  float* Sb = Sg + ((long long)b * 136 + idx) * TILE_E;
#pragma unroll
  for (int i = 0; i < 2; ++i)
#pragma unroll
    for (int j = 0; j < 2; ++j)
#pragma unroll
      for (int e = 0; e < 16; ++e) {
        int row = wr * 64 + i * 32 + (e & 3) + 8 * (e >> 2) + 4 * lh;
        int col = wc * 64 + j * 32 + l31;
        Sb[(long long)row * 128 + col] = acc[i][j][e];
      }
}

// ---------------------------------------------------------------------------
// Row softmax over packed triangular tiles (causal, *32). P bf16 in place.
// ---------------------------------------------------------------------------
__global__ __launch_bounds__(256) void softmax_kernel(float* __restrict__ Sg)
{
  __shared__ float red[8];
  int blk = blockIdx.x;
  int b = blk >> 11, s = blk & 2047;
  int st = s >> 7, r = s & 127;
  long long tri = (long long)st * (st + 1) / 2;
  const float* tb = Sg + ((long long)b * 136 + tri) * TILE_E + (long long)r * 128;

  int tid = threadIdx.x;
  int lane = tid & 63, wid = tid >> 6;

  int c0 = tid * 8;
  int tt = c0 >> 7, cc = c0 & 127;
  bool live = (c0 <= s);
  f32x4 v0 = {0.f, 0.f, 0.f, 0.f}, v1 = {0.f, 0.f, 0.f, 0.f};
  if (live) {
    const float* seg = tb + (long long)tt * TILE_E + cc;
    v0 = *(const f32x4*)seg;
    v1 = *(const f32x4*)(seg + 4);
  }

  float m = -3.0e38f;
#pragma unroll
  for (int e = 0; e < 4; ++e) {
    if (c0 + e <= s) m = fmaxf(m, v0[e]);
    if (c0 + 4 + e <= s) m = fmaxf(m, v1[e]);
  }
#pragma unroll
  for (int o = 32; o > 0; o >>= 1) m = fmaxf(m, __shfl_xor(m, o));
  if (lane == 0) red[wid] = m;
  __syncthreads();
  m = fmaxf(fmaxf(red[0], red[1]), fmaxf(red[2], red[3]));

  const float C = 46.16624130844683f;  // 32 * log2(e)
  float p0[4], p1[4];
  float sum = 0.f;
#pragma unroll
  for (int e = 0; e < 4; ++e) {
    p0[e] = (c0 + e <= s) ? exp2f((v0[e] - m) * C) : 0.f;
    sum += p0[e];
    p1[e] = (c0 + 4 + e <= s) ? exp2f((v1[e] - m) * C) : 0.f;
    sum += p1[e];
  }
#pragma unroll
  for (int o = 32; o > 0; o >>= 1) sum += __shfl_xor(sum, o);
  if (lane == 0) red[4 + wid] = sum;
  __syncthreads();
  float inv = 1.f / (red[4] + red[5] + red[6] + red[7]);

  union { bf16x8 v; s16x4 h[2]; } w;
#pragma unroll
  for (int e = 0; e < 4; ++e) {
    w.h[0][e] = (short)f2bf(p0[e] * inv);
    w.h[1][e] = (short)f2bf(p1[e] * inv);
  }
  __syncthreads();
  if (c0 < (st + 1) * 128) {
    unsigned short* pw = (unsigned short*)Sg +
        (((long long)b * 136 + tri + tt) * TILE_E) * 2 + (long long)r * 256 + cc;
    *(bf16x8*)pw = w.v;
  }
}

// ---------------------------------------------------------------------------
// PV: O[s,d] = sum_t P[s,t]*vT[d,t]. Issue-early depth-2; longest first.
// ---------------------------------------------------------------------------
__global__ __launch_bounds__(256, 2) void pv_bt(
    const unsigned short* __restrict__ P, const unsigned short* __restrict__ vT,
    float* __restrict__ Out)
{
  __shared__ short lds[2 * 8192];

  int tid = threadIdx.x;
  int lane = tid & 63, wid = tid >> 6;
  int wr = wid >> 1, wc = wid & 1;
  int l15 = lane & 15, lq = lane >> 4;

  int wg = xcd_swizzle(blockIdx.x, gridDim.x);
  int b = wg >> 7;
  int rem = wg & 127;
  int st = 15 - (rem >> 3);
  int dt = rem & 7;

  const unsigned short* Ps = P + ((long long)b * 136 + (long long)st * (st + 1) / 2) * (TILE_E * 2);
  const unsigned short* Vb = vT + (long long)b * DD * TT + (long long)dt * 128 * TT;
  int NT = (st + 1) * 4;

  f32x4 acc[4][4];
#pragma unroll
  for (int i = 0; i < 4; ++i)
#pragma unroll
    for (int j = 0; j < 4; ++j) acc[i][j] = (f32x4){0.f, 0.f, 0.f, 0.f};

  auto stage = [&](int t, int h) {
    int t0 = t * 32;
    const unsigned short* s0 = Ps + (long long)(t0 >> 7) * (TILE_E * 2) + (t0 & 127);
    stage_pair(s0, 256, Vb + t0, TT, lds + h * 8192, tid);
  };

  stage(0, 0);
  stage(1, 1);
  for (int t = 0; t < NT; ++t) {
    int h = t & 1;
    if (t < NT - 1) WAITBAR(4); else WAITBAR(0);
    const short* W = lds + h * 8192;
    bf16x8 af[4], bfr[4];
#pragma unroll
    for (int i = 0; i < 4; ++i) {
      int ra = wr * 64 + i * 16 + l15;
      af[i] = *(const bf16x8*)(&W[((ra * 128 + lq * 16) ^ ((ra & 7) << 4)) >> 1]);
      int rb = wc * 64 + i * 16 + l15;
      bfr[i] = *(const bf16x8*)(&W[((rb * 128 + 64 + lq * 16) ^ ((rb & 7) << 4)) >> 1]);
    }
    BAR();
    if (t + 2 < NT) stage(t + 2, h);
    __builtin_amdgcn_s_setprio(1);
#pragma unroll
    for (int i = 0; i < 4; ++i)
#pragma unroll
      for (int j = 0; j < 4; ++j)
        acc[i][j] = __builtin_amdgcn_mfma_f32_16x16x32_bf16(af[i], bfr[j], acc[i][j], 0, 0, 0);
    __builtin_amdgcn_s_setprio(0);
  }

  float* Ob = Out + (long long)b * SS * DD;
#pragma unroll
  for (int i = 0; i < 4; ++i)
#pragma unroll
    for (int j = 0; j < 4; ++j)
#pragma unroll
      for (int e = 0; e < 4; ++e) {
        int row = st * 128 + wr * 64 + i * 16 + lq * 4 + e;
        int col = dt * 128 + wc * 64 + j * 16 + l15;
        Ob[(long long)row * DD + col] = acc[i][j][e];
      }
}

// ---------------------------------------------------------------------------
extern "C" void kernel_launch(void* const* d_in, const int* in_sizes, int n_in,
                              void* d_out, int out_size, void* d_ws, size_t ws_size,
                              hipStream_t stream) {
  (void)in_sizes; (void)n_in; (void)out_size;
  const float* key   = (const float*)d_in[0];
  const float* query = (const float*)d_in[1];
  const float* value = (const float*)d_in[2];
  const float* Wq    = (const float*)d_in[3];
  const float* Wk    = (const float*)d_in[4];
  const float* Wv    = (const float*)d_in[5];
  float* Out = (float*)d_out;

  const long long SD = (long long)SS * DD;
  const long long DT = (long long)DD * TT;
  const long long WN = (long long)DD * DD;

  const unsigned long long PLANE_B  = (unsigned long long)SD * 2;
  const unsigned long long WPLANE_B = (unsigned long long)WN * 2;
  const unsigned long long SCORE_B  = 136ull * TILE_E * 4;

  auto need = [&](int g) -> unsigned long long {
    return 3ull * WPLANE_B + (unsigned long long)g * (SCORE_B + 5ull * PLANE_B);
  };
  int G = 1;
  for (int g : {8, 4, 2, 1}) if (ws_size >= need(g)) { G = g; break; }

  char* ws = (char*)d_ws;
  size_t off = 0;
  auto alloc = [&](unsigned long long bytes) { char* p = ws + off; off += bytes; return p; };

  unsigned short* mph = (unsigned short*)alloc(WPLANE_B);
  unsigned short* mpl = (unsigned short*)alloc(WPLANE_B);
  unsigned short* wvh = (unsigned short*)alloc(WPLANE_B);
  char* slab = alloc((unsigned long long)G * SCORE_B);
  unsigned short* qh  = (unsigned short*)alloc((unsigned long long)G * PLANE_B);
  unsigned short* ql  = (unsigned short*)alloc((unsigned long long)G * PLANE_B);
  unsigned short* kh  = (unsigned short*)alloc((unsigned long long)G * PLANE_B);
  unsigned short* kl  = (unsigned short*)alloc((unsigned long long)G * PLANE_B);
  unsigned short* vT  = (unsigned short*)alloc((unsigned long long)G * PLANE_B);

  unsigned short* wqTh = (unsigned short*)slab;
  unsigned short* wqTl = (unsigned short*)(slab + WPLANE_B);
  unsigned short* wkTh = (unsigned short*)(slab + 2 * WPLANE_B);
  unsigned short* wkTl = (unsigned short*)(slab + 3 * WPLANE_B);

  unsigned short* iah = (unsigned short*)slab;
  unsigned short* ial = (unsigned short*)(slab + (unsigned long long)G * PLANE_B);
  float* Sg = (float*)slab;

  // M' = Wk^T Wq (hi+lo), tiny 1024^3
  tsplit_k<<<256, 256, 0, stream>>>(Wq, wqTh, wqTl);
  tsplit_k<<<256, 256, 0, stream>>>(Wk, wkTh, wkTl);
  split_h_k<<<512, 256, 0, stream>>>(Wv, wvh, WN / 4);
  gemm_bt<3, true><<<32, 256, 0, stream>>>(
      wkTh, wkTl, wqTh, wqTl, mph, mpl, DD, DD, 0, 0, 0, 8, 8);

  for (int b0 = 0; b0 < NB; b0 += G) {
    long long n4 = (long long)G * SD / 4;
    // z = x M'^T
    split_hl_k<<<2048, 256, 0, stream>>>(query + (long long)b0 * SD, iah, ial, n4);
    gemm_bt<3, true><<<G * 64, 256, 0, stream>>>(
        iah, ial, mph, mpl, qh, ql, DD, DD, SD, 0, SD, 16, 8);
    // key: exact hi/lo split (B operand of the score GEMM)
    split_hl_k<<<2048, 256, 0, stream>>>(key + (long long)b0 * SD, kh, kl, n4);
    // vT = Wv @ value^T
    split_h_k<<<2048, 256, 0, stream>>>(value + (long long)b0 * SD, iah, n4);
    gemm_bt<1, false><<<G * 64, 256, 0, stream>>>(
        wvh, nullptr, iah, nullptr, vT, nullptr, TT, DD, 0, SD, DT, 8, 16);
    // scores = z key^T (triangular), softmax, PV
    qk_bt<<<G * 136, 256, 0, stream>>>(qh, ql, kh, kl, Sg);
    softmax_kernel<<<G * SS, 256, 0, stream>>>(Sg);
    pv_bt<<<G * 128, 256, 0, stream>>>(
        (const unsigned short*)Sg, vT, Out + (long long)b0 * SD);
  }
}

// Round 17
// 480.680 us; speedup vs baseline: 1.0150x; 1.0150x over previous
//
#include <hip/hip_runtime.h>
#include <hip/hip_bf16.h>

// AttentionLayer: out = softmax(32 * (xWq^T)(yWk^T)^T + causal) @ (zWv^T)
// N=8, S=T=2048, D=1024. All f32 in/out.
//
// R17 = R14 verbatim (best: 480.2us). R16's 32x32-MFMA qk was correct but
// regressed via 4-way LDS bank conflicts (8.9M/dispatch: rows r,r+8,r+16,
// r+24 share the XOR slot under a 32-row fragment span) -> reverted.
// Composed floor at demonstrated rates: ~320us GEMM @ ~880 TF structure
// ceiling (7 experiments pinned MfmaUtil 36-38%) + ~65us BW-bound splits
// + ~28us softmax + launch gaps = ~480us.

typedef __attribute__((ext_vector_type(4))) float f32x4;
typedef __attribute__((ext_vector_type(8))) short bf16x8;
typedef __attribute__((ext_vector_type(4))) short s16x4;

#define DEVI __device__ __forceinline__

DEVI unsigned short f2bf(float x) {
  union { float f; unsigned u; } v; v.f = x;
  unsigned r = v.u + 0x7FFFu + ((v.u >> 16) & 1u);
  return (unsigned short)(r >> 16);
}
DEVI float bf2f(unsigned short b) {
  union { float f; unsigned u; } v; v.u = ((unsigned)b) << 16;
  return v.f;
}

DEVI void gload16(const void* g, void* l) {
#if __has_builtin(__builtin_amdgcn_global_load_lds)
  typedef __attribute__((address_space(1))) const unsigned int* gas_u32;
  typedef __attribute__((address_space(3))) unsigned int* las_u32;
  __builtin_amdgcn_global_load_lds(
      (gas_u32)(unsigned long long)g,
      (las_u32)(unsigned int)(unsigned long long)l, 16, 0, 0);
#else
  *(bf16x8*)l = *(const bf16x8*)g;
#endif
}

DEVI int xcd_swizzle(int bid, int nwg) {
  if (nwg & 7) return bid;
  int cpx = nwg >> 3;
  return (bid & 7) * cpx + (bid >> 3);
}

#define WAITBAR(N) asm volatile("s_waitcnt vmcnt(" #N ")\ns_barrier" ::: "memory")
#define BAR()      asm volatile("s_barrier" ::: "memory")

// Stage one combined plane: 128 rows x 128B, row = [s0 64B | s1 64B],
// XOR-swizzled (chunk ^= row&7), linear LDS dest (256-thread blocks).
DEVI void stage_pair(const unsigned short* __restrict__ s0, long long rs0,
                     const unsigned short* __restrict__ s1, long long rs1,
                     short* lds, int tid) {
#pragma unroll
  for (int it = 0; it < 4; ++it) {
    int ii = it * 256 + tid;
    int r = ii >> 3;
    int c8 = (ii & 7) ^ (r & 7);
    const unsigned short* src = (c8 < 4)
        ? s0 + (long long)r * rs0 + (c8 & 3) * 8
        : s1 + (long long)r * rs1 + (c8 & 3) * 8;
    gload16(src, &lds[ii * 8]);
  }
}

constexpr int NB = 8, SS = 2048, TT = 2048, DD = 1024;
constexpr long long TILE_E = 16384;

// ---------------------------------------------------------------------------
// Elementwise split kernels.
// ---------------------------------------------------------------------------
__global__ __launch_bounds__(256) void split_hl_k(
    const float* __restrict__ in, unsigned short* __restrict__ hi,
    unsigned short* __restrict__ lo, long long n4)
{
  long long i = (long long)blockIdx.x * 256 + threadIdx.x;
  long long stride = (long long)gridDim.x * 256;
  for (; i < n4; i += stride) {
    f32x4 v = ((const f32x4*)in)[i];
    s16x4 h, l;
#pragma unroll
    for (int e = 0; e < 4; ++e) {
      unsigned short hh = f2bf(v[e]);
      h[e] = (short)hh;
      l[e] = (short)f2bf(v[e] - bf2f(hh));
    }
    ((s16x4*)hi)[i] = h;
    ((s16x4*)lo)[i] = l;
  }
}

__global__ __launch_bounds__(256) void split_h_k(
    const float* __restrict__ in, unsigned short* __restrict__ hi, long long n4)
{
  long long i = (long long)blockIdx.x * 256 + threadIdx.x;
  long long stride = (long long)gridDim.x * 256;
  for (; i < n4; i += stride) {
    f32x4 v = ((const f32x4*)in)[i];
    s16x4 h;
#pragma unroll
    for (int e = 0; e < 4; ++e) h[e] = (short)f2bf(v[e]);
    ((s16x4*)hi)[i] = h;
  }
}

// Transpose + split weights (tiny).
__global__ __launch_bounds__(256) void tsplit_k(
    const float* __restrict__ W, unsigned short* __restrict__ Th,
    unsigned short* __restrict__ Tl)
{
  __shared__ float t[64][68];
  int bi = blockIdx.x & 15, bj = blockIdx.x >> 4;
  int tid = threadIdx.x;
  int lr = tid >> 2, lc4 = tid & 3;
#pragma unroll
  for (int q = 0; q < 4; ++q) {
    int col = (lc4 + q * 4) * 4;
    f32x4 v = *(const f32x4*)(W + (long long)(bj * 64 + lr) * DD + bi * 64 + col);
    t[lr][col] = v[0]; t[lr][col + 1] = v[1];
    t[lr][col + 2] = v[2]; t[lr][col + 3] = v[3];
  }
  __syncthreads();
  int orow = tid >> 2, ch = tid & 3;
#pragma unroll
  for (int cc = 0; cc < 2; ++cc) {
    int c0 = (ch + cc * 4) * 8;
    bf16x8 h, l;
#pragma unroll
    for (int e = 0; e < 8; ++e) {
      float v = t[c0 + e][orow];
      unsigned short hh = f2bf(v);
      h[e] = (short)hh;
      l[e] = (short)f2bf(v - bf2f(hh));
    }
    long long o = (long long)(bi * 64 + orow) * DD + bj * 64 + c0;
    *(bf16x8*)(Th + o) = h;
    *(bf16x8*)(Tl + o) = l;
  }
}

// ---------------------------------------------------------------------------
// bt-GEMM (128^2, 2 M-tiles/block, depth-2 counted vmcnt, issue-early).
// ---------------------------------------------------------------------------
template<int NMFMA, bool SPLIT_OUT>
__global__ __launch_bounds__(256, 2) void gemm_bt(
    const unsigned short* __restrict__ Ah_g, const unsigned short* __restrict__ Al_g,
    const unsigned short* __restrict__ Bh_g, const unsigned short* __restrict__ Bl_g,
    unsigned short* __restrict__ Chi, unsigned short* __restrict__ Clo,
    int Nn, int K,
    long long aStride, long long bStride, long long cStride,
    int tilesM, int tilesN)
{
  constexpr int HALF = (NMFMA == 3) ? 16384 : 8192;
  __shared__ short lds[2 * HALF];

  int tid = threadIdx.x;
  int lane = tid & 63, wid = tid >> 6;
  int wr = wid >> 1, wc = wid & 1;
  int l15 = lane & 15, lq = lane >> 4;

  int wg = xcd_swizzle(blockIdx.x, gridDim.x);
  int tilesM2 = tilesM >> 1;
  int tilesPer = tilesM2 * tilesN;
  int b = wg / tilesPer;
  int rem = wg % tilesPer;
  int mt2 = rem / tilesN, nt = rem % tilesN;

  const unsigned short* Bgh = Bh_g + (long long)b * bStride + (long long)nt * 128 * K;
  const unsigned short* Bgl = (NMFMA == 3) ? Bl_g + (long long)b * bStride + (long long)nt * 128 * K : nullptr;

  for (int hm = 0; hm < 2; ++hm) {
    int mt = mt2 + hm * tilesM2;
    const unsigned short* Agh = Ah_g + (long long)b * aStride + (long long)mt * 128 * K;
    const unsigned short* Agl = (NMFMA == 3) ? Al_g + (long long)b * aStride + (long long)mt * 128 * K : nullptr;

    f32x4 acc[4][4];
#pragma unroll
    for (int i = 0; i < 4; ++i)
#pragma unroll
      for (int j = 0; j < 4; ++j) acc[i][j] = (f32x4){0.f, 0.f, 0.f, 0.f};

    auto stage = [&](int t, int h) {
      int k0 = t * 32;
      if constexpr (NMFMA == 3) {
        stage_pair(Agh + k0, K, Agl + k0, K, lds + h * HALF, tid);
        stage_pair(Bgh + k0, K, Bgl + k0, K, lds + h * HALF + 8192, tid);
      } else {
        stage_pair(Agh + k0, K, Bgh + k0, K, lds + h * HALF, tid);
      }
    };

    int NT = K >> 5;
    stage(0, 0);
    stage(1, 1);
    for (int t = 0; t < NT; ++t) {
      int h = t & 1;
      if (t < NT - 1) {
        if constexpr (NMFMA == 3) WAITBAR(8); else WAITBAR(4);
      } else {
        WAITBAR(0);
      }
      if constexpr (NMFMA == 3) {
        const short* U = lds + h * HALF;
        const short* V = U + 8192;
        bf16x8 afh[4], afl[4], bfh[4], bfl[4];
#pragma unroll
        for (int i = 0; i < 4; ++i) {
          int ra = wr * 64 + i * 16 + l15;
          int sa = (ra & 7) << 4;
          afh[i] = *(const bf16x8*)(&U[((ra * 128 + lq * 16) ^ sa) >> 1]);
          afl[i] = *(const bf16x8*)(&U[((ra * 128 + 64 + lq * 16) ^ sa) >> 1]);
          int rb = wc * 64 + i * 16 + l15;
          int sb = (rb & 7) << 4;
          bfh[i] = *(const bf16x8*)(&V[((rb * 128 + lq * 16) ^ sb) >> 1]);
          bfl[i] = *(const bf16x8*)(&V[((rb * 128 + 64 + lq * 16) ^ sb) >> 1]);
        }
        BAR();
        if (t + 2 < NT) stage(t + 2, h);
        __builtin_amdgcn_s_setprio(1);
#pragma unroll
        for (int i = 0; i < 4; ++i)
#pragma unroll
          for (int j = 0; j < 4; ++j) {
            acc[i][j] = __builtin_amdgcn_mfma_f32_16x16x32_bf16(afh[i], bfh[j], acc[i][j], 0, 0, 0);
            acc[i][j] = __builtin_amdgcn_mfma_f32_16x16x32_bf16(afh[i], bfl[j], acc[i][j], 0, 0, 0);
            acc[i][j] = __builtin_amdgcn_mfma_f32_16x16x32_bf16(afl[i], bfh[j], acc[i][j], 0, 0, 0);
          }
        __builtin_amdgcn_s_setprio(0);
      } else {
        const short* W = lds + h * HALF;
        bf16x8 af[4], bfr[4];
#pragma unroll
        for (int i = 0; i < 4; ++i) {
          int ra = wr * 64 + i * 16 + l15;
          af[i] = *(const bf16x8*)(&W[((ra * 128 + lq * 16) ^ ((ra & 7) << 4)) >> 1]);
          int rb = wc * 64 + i * 16 + l15;
          bfr[i] = *(const bf16x8*)(&W[((rb * 128 + 64 + lq * 16) ^ ((rb & 7) << 4)) >> 1]);
        }
        BAR();
        if (t + 2 < NT) stage(t + 2, h);
        __builtin_amdgcn_s_setprio(1);
#pragma unroll
        for (int i = 0; i < 4; ++i)
#pragma unroll
          for (int j = 0; j < 4; ++j)
            acc[i][j] = __builtin_amdgcn_mfma_f32_16x16x32_bf16(af[i], bfr[j], acc[i][j], 0, 0, 0);
        __builtin_amdgcn_s_setprio(0);
      }
    }

    unsigned short* ch = Chi + (long long)b * cStride;
    unsigned short* cl = SPLIT_OUT ? (Clo + (long long)b * cStride) : nullptr;
#pragma unroll
    for (int i = 0; i < 4; ++i)
#pragma unroll
      for (int j = 0; j < 4; ++j)
#pragma unroll
        for (int e = 0; e < 4; ++e) {
          int row = mt * 128 + wr * 64 + i * 16 + lq * 4 + e;
          int col = nt * 128 + wc * 64 + j * 16 + l15;
          float vv = acc[i][j][e];
          unsigned short h = f2bf(vv);
          ch[(long long)row * Nn + col] = h;
          if constexpr (SPLIT_OUT) cl[(long long)row * Nn + col] = f2bf(vv - bf2f(h));
        }
    BAR();
  }
}

// ---------------------------------------------------------------------------
// QK^T: bf16x3, 128x128 lower-triangular tiles, packed output. Issue-early.
// ---------------------------------------------------------------------------
__global__ __launch_bounds__(256, 2) void qk_bt(
    const unsigned short* __restrict__ qh, const unsigned short* __restrict__ ql,
    const unsigned short* __restrict__ kh, const unsigned short* __restrict__ kl,
    float* __restrict__ Sg)
{
  __shared__ short lds[2 * 16384];

  int tid = threadIdx.x;
  int lane = tid & 63, wid = tid >> 6;
  int wr = wid >> 1, wc = wid & 1;
  int l15 = lane & 15, lq = lane >> 4;

  int wg = xcd_swizzle(blockIdx.x, gridDim.x);
  int b = wg / 136;
  int idx = wg % 136;
  int st = (int)((sqrtf(8.f * (float)idx + 1.f) - 1.f) * 0.5f);
  while ((st + 1) * (st + 2) / 2 <= idx) ++st;
  while (st * (st + 1) / 2 > idx) --st;
  int tt = idx - st * (st + 1) / 2;

  const unsigned short* Agh = qh + (long long)b * SS * DD + (long long)st * 128 * DD;
  const unsigned short* Agl = ql + (long long)b * SS * DD + (long long)st * 128 * DD;
  const unsigned short* Bgh = kh + (long long)b * TT * DD + (long long)tt * 128 * DD;
  const unsigned short* Bgl = kl + (long long)b * TT * DD + (long long)tt * 128 * DD;

  f32x4 acc[4][4];
#pragma unroll
  for (int i = 0; i < 4; ++i)
#pragma unroll
    for (int j = 0; j < 4; ++j) acc[i][j] = (f32x4){0.f, 0.f, 0.f, 0.f};

  auto stage = [&](int t, int h) {
    int k0 = t * 32;
    stage_pair(Agh + k0, DD, Agl + k0, DD, lds + h * 16384, tid);
    stage_pair(Bgh + k0, DD, Bgl + k0, DD, lds + h * 16384 + 8192, tid);
  };

  stage(0, 0);
  stage(1, 1);
  for (int t = 0; t < 32; ++t) {
    int h = t & 1;
    if (t < 31) WAITBAR(8); else WAITBAR(0);
    const short* U = lds + h * 16384;
    const short* V = U + 8192;
    bf16x8 afh[4], afl[4], bfh[4], bfl[4];
#pragma unroll
    for (int i = 0; i < 4; ++i) {
      int ra = wr * 64 + i * 16 + l15;
      int sa = (ra & 7) << 4;
      afh[i] = *(const bf16x8*)(&U[((ra * 128 + lq * 16) ^ sa) >> 1]);
      afl[i] = *(const bf16x8*)(&U[((ra * 128 + 64 + lq * 16) ^ sa) >> 1]);
      int rb = wc * 64 + i * 16 + l15;
      int sb = (rb & 7) << 4;
      bfh[i] = *(const bf16x8*)(&V[((rb * 128 + lq * 16) ^ sb) >> 1]);
      bfl[i] = *(const bf16x8*)(&V[((rb * 128 + 64 + lq * 16) ^ sb) >> 1]);
    }
    BAR();
    if (t + 2 < 32) stage(t + 2, h);
    __builtin_amdgcn_s_setprio(1);
#pragma unroll
    for (int i = 0; i < 4; ++i)
#pragma unroll
      for (int j = 0; j < 4; ++j) {
        acc[i][j] = __builtin_amdgcn_mfma_f32_16x16x32_bf16(afh[i], bfh[j], acc[i][j], 0, 0, 0);
        acc[i][j] = __builtin_amdgcn_mfma_f32_16x16x32_bf16(afh[i], bfl[j], acc[i][j], 0, 0, 0);
        acc[i][j] = __builtin_amdgcn_mfma_f32_16x16x32_bf16(afl[i], bfh[j], acc[i][j], 0, 0, 0);
      }
    __builtin_amdgcn_s_setprio(0);
  }

  float* Sb = Sg + ((long long)b * 136 + idx) * TILE_E;
#pragma unroll
  for (int i = 0; i < 4; ++i)
#pragma unroll
    for (int j = 0; j < 4; ++j)
#pragma unroll
      for (int e = 0; e < 4; ++e) {
        int row = wr * 64 + i * 16 + lq * 4 + e;
        int col = wc * 64 + j * 16 + l15;
        Sb[(long long)row * 128 + col] = acc[i][j][e];
      }
}

// ---------------------------------------------------------------------------
// Row softmax over packed triangular tiles (causal, *32). P bf16 in place.
// ---------------------------------------------------------------------------
__global__ __launch_bounds__(256) void softmax_kernel(float* __restrict__ Sg)
{
  __shared__ float red[8];
  int blk = blockIdx.x;
  int b = blk >> 11, s = blk & 2047;
  int st = s >> 7, r = s & 127;
  long long tri = (long long)st * (st + 1) / 2;
  const float* tb = Sg + ((long long)b * 136 + tri) * TILE_E + (long long)r * 128;

  int tid = threadIdx.x;
  int lane = tid & 63, wid = tid >> 6;

  int c0 = tid * 8;
  int tt = c0 >> 7, cc = c0 & 127;
  bool live = (c0 <= s);
  f32x4 v0 = {0.f, 0.f, 0.f, 0.f}, v1 = {0.f, 0.f, 0.f, 0.f};
  if (live) {
    const float* seg = tb + (long long)tt * TILE_E + cc;
    v0 = *(const f32x4*)seg;
    v1 = *(const f32x4*)(seg + 4);
  }

  float m = -3.0e38f;
#pragma unroll
  for (int e = 0; e < 4; ++e) {
    if (c0 + e <= s) m = fmaxf(m, v0[e]);
    if (c0 + 4 + e <= s) m = fmaxf(m, v1[e]);
  }
#pragma unroll
  for (int o = 32; o > 0; o >>= 1) m = fmaxf(m, __shfl_xor(m, o));
  if (lane == 0) red[wid] = m;
  __syncthreads();
  m = fmaxf(fmaxf(red[0], red[1]), fmaxf(red[2], red[3]));

  const float C = 46.16624130844683f;  // 32 * log2(e)
  float p0[4], p1[4];
  float sum = 0.f;
#pragma unroll
  for (int e = 0; e < 4; ++e) {
    p0[e] = (c0 + e <= s) ? exp2f((v0[e] - m) * C) : 0.f;
    sum += p0[e];
    p1[e] = (c0 + 4 + e <= s) ? exp2f((v1[e] - m) * C) : 0.f;
    sum += p1[e];
  }
#pragma unroll
  for (int o = 32; o > 0; o >>= 1) sum += __shfl_xor(sum, o);
  if (lane == 0) red[4 + wid] = sum;
  __syncthreads();
  float inv = 1.f / (red[4] + red[5] + red[6] + red[7]);

  union { bf16x8 v; s16x4 h[2]; } w;
#pragma unroll
  for (int e = 0; e < 4; ++e) {
    w.h[0][e] = (short)f2bf(p0[e] * inv);
    w.h[1][e] = (short)f2bf(p1[e] * inv);
  }
  __syncthreads();
  if (c0 < (st + 1) * 128) {
    unsigned short* pw = (unsigned short*)Sg +
        (((long long)b * 136 + tri + tt) * TILE_E) * 2 + (long long)r * 256 + cc;
    *(bf16x8*)pw = w.v;
  }
}

// ---------------------------------------------------------------------------
// PV: O[s,d] = sum_t P[s,t]*vT[d,t]. Issue-early depth-2; longest first.
// ---------------------------------------------------------------------------
__global__ __launch_bounds__(256, 2) void pv_bt(
    const unsigned short* __restrict__ P, const unsigned short* __restrict__ vT,
    float* __restrict__ Out)
{
  __shared__ short lds[2 * 8192];

  int tid = threadIdx.x;
  int lane = tid & 63, wid = tid >> 6;
  int wr = wid >> 1, wc = wid & 1;
  int l15 = lane & 15, lq = lane >> 4;

  int wg = xcd_swizzle(blockIdx.x, gridDim.x);
  int b = wg >> 7;
  int rem = wg & 127;
  int st = 15 - (rem >> 3);
  int dt = rem & 7;

  const unsigned short* Ps = P + ((long long)b * 136 + (long long)st * (st + 1) / 2) * (TILE_E * 2);
  const unsigned short* Vb = vT + (long long)b * DD * TT + (long long)dt * 128 * TT;
  int NT = (st + 1) * 4;

  f32x4 acc[4][4];
#pragma unroll
  for (int i = 0; i < 4; ++i)
#pragma unroll
    for (int j = 0; j < 4; ++j) acc[i][j] = (f32x4){0.f, 0.f, 0.f, 0.f};

  auto stage = [&](int t, int h) {
    int t0 = t * 32;
    const unsigned short* s0 = Ps + (long long)(t0 >> 7) * (TILE_E * 2) + (t0 & 127);
    stage_pair(s0, 256, Vb + t0, TT, lds + h * 8192, tid);
  };

  stage(0, 0);
  stage(1, 1);
  for (int t = 0; t < NT; ++t) {
    int h = t & 1;
    if (t < NT - 1) WAITBAR(4); else WAITBAR(0);
    const short* W = lds + h * 8192;
    bf16x8 af[4], bfr[4];
#pragma unroll
    for (int i = 0; i < 4; ++i) {
      int ra = wr * 64 + i * 16 + l15;
      af[i] = *(const bf16x8*)(&W[((ra * 128 + lq * 16) ^ ((ra & 7) << 4)) >> 1]);
      int rb = wc * 64 + i * 16 + l15;
      bfr[i] = *(const bf16x8*)(&W[((rb * 128 + 64 + lq * 16) ^ ((rb & 7) << 4)) >> 1]);
    }
    BAR();
    if (t + 2 < NT) stage(t + 2, h);
    __builtin_amdgcn_s_setprio(1);
#pragma unroll
    for (int i = 0; i < 4; ++i)
#pragma unroll
      for (int j = 0; j < 4; ++j)
        acc[i][j] = __builtin_amdgcn_mfma_f32_16x16x32_bf16(af[i], bfr[j], acc[i][j], 0, 0, 0);
    __builtin_amdgcn_s_setprio(0);
  }

  float* Ob = Out + (long long)b * SS * DD;
#pragma unroll
  for (int i = 0; i < 4; ++i)
#pragma unroll
    for (int j = 0; j < 4; ++j)
#pragma unroll
      for (int e = 0; e < 4; ++e) {
        int row = st * 128 + wr * 64 + i * 16 + lq * 4 + e;
        int col = dt * 128 + wc * 64 + j * 16 + l15;
        Ob[(long long)row * DD + col] = acc[i][j][e];
      }
}

// ---------------------------------------------------------------------------
extern "C" void kernel_launch(void* const* d_in, const int* in_sizes, int n_in,
                              void* d_out, int out_size, void* d_ws, size_t ws_size,
                              hipStream_t stream) {
  (void)in_sizes; (void)n_in; (void)out_size;
  const float* key   = (const float*)d_in[0];
  const float* query = (const float*)d_in[1];
  const float* value = (const float*)d_in[2];
  const float* Wq    = (const float*)d_in[3];
  const float* Wk    = (const float*)d_in[4];
  const float* Wv    = (const float*)d_in[5];
  float* Out = (float*)d_out;

  const long long SD = (long long)SS * DD;
  const long long DT = (long long)DD * TT;
  const long long WN = (long long)DD * DD;

  const unsigned long long PLANE_B  = (unsigned long long)SD * 2;
  const unsigned long long WPLANE_B = (unsigned long long)WN * 2;
  const unsigned long long SCORE_B  = 136ull * TILE_E * 4;

  auto need = [&](int g) -> unsigned long long {
    return 3ull * WPLANE_B + (unsigned long long)g * (SCORE_B + 5ull * PLANE_B);
  };
  int G = 1;
  for (int g : {8, 4, 2, 1}) if (ws_size >= need(g)) { G = g; break; }

  char* ws = (char*)d_ws;
  size_t off = 0;
  auto alloc = [&](unsigned long long bytes) { char* p = ws + off; off += bytes; return p; };

  unsigned short* mph = (unsigned short*)alloc(WPLANE_B);
  unsigned short* mpl = (unsigned short*)alloc(WPLANE_B);
  unsigned short* wvh = (unsigned short*)alloc(WPLANE_B);
  char* slab = alloc((unsigned long long)G * SCORE_B);
  unsigned short* qh  = (unsigned short*)alloc((unsigned long long)G * PLANE_B);
  unsigned short* ql  = (unsigned short*)alloc((unsigned long long)G * PLANE_B);
  unsigned short* kh  = (unsigned short*)alloc((unsigned long long)G * PLANE_B);
  unsigned short* kl  = (unsigned short*)alloc((unsigned long long)G * PLANE_B);
  unsigned short* vT  = (unsigned short*)alloc((unsigned long long)G * PLANE_B);

  unsigned short* wqTh = (unsigned short*)slab;
  unsigned short* wqTl = (unsigned short*)(slab + WPLANE_B);
  unsigned short* wkTh = (unsigned short*)(slab + 2 * WPLANE_B);
  unsigned short* wkTl = (unsigned short*)(slab + 3 * WPLANE_B);

  unsigned short* iah = (unsigned short*)slab;
  unsigned short* ial = (unsigned short*)(slab + (unsigned long long)G * PLANE_B);
  float* Sg = (float*)slab;

  // M' = Wk^T Wq (hi+lo), tiny 1024^3
  tsplit_k<<<256, 256, 0, stream>>>(Wq, wqTh, wqTl);
  tsplit_k<<<256, 256, 0, stream>>>(Wk, wkTh, wkTl);
  split_h_k<<<512, 256, 0, stream>>>(Wv, wvh, WN / 4);
  gemm_bt<3, true><<<32, 256, 0, stream>>>(
      wkTh, wkTl, wqTh, wqTl, mph, mpl, DD, DD, 0, 0, 0, 8, 8);

  for (int b0 = 0; b0 < NB; b0 += G) {
    long long n4 = (long long)G * SD / 4;
    // z = x M'^T
    split_hl_k<<<2048, 256, 0, stream>>>(query + (long long)b0 * SD, iah, ial, n4);
    gemm_bt<3, true><<<G * 64, 256, 0, stream>>>(
        iah, ial, mph, mpl, qh, ql, DD, DD, SD, 0, SD, 16, 8);
    // key: exact hi/lo split (B operand of the score GEMM)
    split_hl_k<<<2048, 256, 0, stream>>>(key + (long long)b0 * SD, kh, kl, n4);
    // vT = Wv @ value^T
    split_h_k<<<2048, 256, 0, stream>>>(value + (long long)b0 * SD, iah, n4);
    gemm_bt<1, false><<<G * 64, 256, 0, stream>>>(
        wvh, nullptr, iah, nullptr, vT, nullptr, TT, DD, 0, SD, DT, 8, 16);
    // scores = z key^T (triangular), softmax, PV
    qk_bt<<<G * 136, 256, 0, stream>>>(qh, ql, kh, kl, Sg);
    softmax_kernel<<<G * SS, 256, 0, stream>>>(Sg);
    pv_bt<<<G * 128, 256, 0, stream>>>(
        (const unsigned short*)Sg, vT, Out + (long long)b0 * SD);
  }
}